// Round 1
// 94.729 us; speedup vs baseline: 1.0854x; 1.0854x over previous
//
#include <hip/hip_runtime.h>

// Problem constants
#define NB   8192
#define ND   256
#define NH1  50
#define NH2  32
#define NH3  18
#define RPB  16              // rows per block
#define NBLK (NB / RPB)      // 512 blocks
#define WSS  40              // per-block ws slot stride (floats)

// ws layout: ws[b*WSS + c], c: [0..17] ysum part, [18..35] colsum(W_user) part,
//            [36] sum(log_denom) part. No atomics, no zero-init needed.

__device__ __forceinline__ float sigmoidf_fast(float v) {
    return 1.0f / (1.0f + __expf(-v));
}

// DPP-based 16-lane-group sum: VALU pipe only (replaces ds_bpermute shuffles).
template <int CTRL>
__device__ __forceinline__ float dpp_addf(float v) {
    return v + __int_as_float(__builtin_amdgcn_update_dpp(
        0, __float_as_int(v), CTRL, 0xF, 0xF, true));
}
__device__ __forceinline__ float sum16(float v) {
    v = dpp_addf<0xB1>(v);    // quad_perm [1,0,3,2] : xor 1
    v = dpp_addf<0x4E>(v);    // quad_perm [2,3,0,1] : xor 2
    v = dpp_addf<0x124>(v);   // row_ror:4 (adds neighbor quad)
    v = dpp_addf<0x128>(v);   // row_ror:8 (adds opposite pair)
    return v;
}

// async global->LDS, 16B per lane, wave-uniform LDS base + lane*16
__device__ __forceinline__ void gload_lds16(const float* g, float* l) {
    __builtin_amdgcn_global_load_lds(
        (const __attribute__((address_space(1))) unsigned int*)g,
        (__attribute__((address_space(3))) unsigned int*)l, 16, 0, 0);
}

__global__ __launch_bounds__(256) void fused_main(
    const float* __restrict__ x, const float* __restrict__ y,
    const float* __restrict__ W1, const float* __restrict__ b1,
    const float* __restrict__ W2, const float* __restrict__ b2,
    const float* __restrict__ W3, const float* __restrict__ b3,
    float* __restrict__ out, float* __restrict__ ws)
{
    // W1 kept ROW-MAJOR [k][j] (no transpose): staged linearly via
    // global_load_lds (no divs, no bank conflicts on write).
    __shared__ alignas(16) float w1l[ND * NH1];    // 51200 B
    __shared__ alignas(16) float w2l[NH1 * NH2];   // 6400 B
    __shared__ alignas(16) float w3l[NH2 * NH3];   // 2304 B
    __shared__ alignas(16) float h2l[RPB][NH2 + 2];// stride 34, 2176 B
    __shared__ alignas(16) float wul[RPB][NH3 + 1];// stride 19, 1216 B
    // total 63296 B -> 2 blocks/CU

    const int t    = threadIdx.x;
    const int row  = t >> 4;          // 0..15 local row
    const int ksl  = t & 15;          // k-slice within row
    const int lane = t & 63;
    const int wave = t >> 6;
    const int grow = blockIdx.x * RPB + row;

    // ---- issue x loads first (registers; stay in flight over staging) ----
    // lane's k-set: {32c + 2ksl, 32c + 2ksl + 1}, c = 0..7  (coalesced float2)
    const float* xrow = x + (size_t)grow * ND + 2 * ksl;
    float2 xv[8];
#pragma unroll
    for (int c = 0; c < 8; ++c)
        xv[c] = *reinterpret_cast<const float2*>(xrow + 32 * c);

    // ---- stage W1 row-major via global_load_lds: 50 chunks of 1024 B ----
#pragma unroll
    for (int i = 0; i < 13; ++i) {
        const int c = wave + 4 * i;            // wave-uniform chunk id
        if (c < 50)
            gload_lds16(W1 + c * 256 + lane * 4, w1l + c * 256);
    }
    for (int e = t; e < NH1 * NH2; e += 256) w2l[e] = W2[e];
    for (int e = t; e < NH2 * NH3; e += 256) w3l[e] = W3[e];
    __syncthreads();

    // ---- layer 1: k-outer over this lane's 16 k values ----
    // Read W1 rows kA=32c+2ksl (even) and kB=kA+1 as float2 chunks.
    // Lane addr stride = 100 dwords == 4 mod 32 -> 16 banks x 2-way = free;
    // 4 row-groups read identical addresses -> broadcast.
    float h1[NH1];
#pragma unroll
    for (int j = 0; j < NH1; ++j) h1[j] = 0.0f;
#pragma unroll
    for (int c = 0; c < 8; ++c) {
        const int kA = 32 * c + 2 * ksl;
        const float* wA = &w1l[kA * NH1];
        const float* wB = wA + NH1;
        const float xa = xv[c].x, xb = xv[c].y;
#pragma unroll
        for (int jj = 0; jj < 25; ++jj) {
            const float2 a = *reinterpret_cast<const float2*>(wA + 2 * jj);
            const float2 b = *reinterpret_cast<const float2*>(wB + 2 * jj);
            h1[2 * jj]     = fmaf(xa, a.x, fmaf(xb, b.x, h1[2 * jj]));
            h1[2 * jj + 1] = fmaf(xa, a.y, fmaf(xb, b.y, h1[2 * jj + 1]));
        }
    }
    // 16-lane reduction on the VALU (DPP), bias + sigmoid
#pragma unroll
    for (int j = 0; j < NH1; ++j)
        h1[j] = sigmoidf_fast(sum16(h1[j]) + b1[j]);

    // ---- layer 2: each lane computes 2 of 32 cols for its row ----
    {
        const float2 bb = *reinterpret_cast<const float2*>(b2 + 2 * ksl);
        float h2a = bb.x, h2b = bb.y;
#pragma unroll
        for (int j = 0; j < NH1; ++j) {
            const float2 w = *reinterpret_cast<const float2*>(&w2l[j * NH2 + 2 * ksl]);
            h2a = fmaf(h1[j], w.x, h2a);
            h2b = fmaf(h1[j], w.y, h2b);
        }
        h2a = sigmoidf_fast(h2a);
        h2b = sigmoidf_fast(h2b);
        *reinterpret_cast<float2*>(&h2l[row][2 * ksl]) = make_float2(h2a, h2b);
    }
    // NO barrier: layer 3 reads only h2l[row][*], written by this lane's own
    // 16-lane group (same wave, lockstep; compiler orders via lgkmcnt).

    // ---- layer 3: lane computes col ksl (and 16+ksl for ksl<2) ----
    {
        float a0 = b3[ksl];
        float a1 = (ksl < 2) ? b3[16 + ksl] : 0.0f;
#pragma unroll
        for (int j = 0; j < NH2; ++j) {
            const float h = h2l[row][j];              // broadcast within 16-group
            a0 = fmaf(h, w3l[j * NH3 + ksl], a0);
            if (ksl < 2) a1 = fmaf(h, w3l[j * NH3 + 16 + ksl], a1);
        }
        wul[row][ksl] = a0;
        out[(size_t)grow * NH3 + ksl] = a0;
        if (ksl < 2) {
            wul[row][16 + ksl] = a1;
            out[(size_t)grow * NH3 + 16 + ksl] = a1;
        }
    }
    __syncthreads();   // epilogue wave reads all 16 rows (cross-wave)

    // ---- epilogue on wave 0: factorized LSE + block reductions ----
    if (t < 64) {
        const bool act = t < RPB;
        float wv[NH3], yv[NH3];
        float ld = 0.0f;
        if (act) {
            const float* yrow = y + (size_t)(blockIdx.x * RPB + t) * NH3;
#pragma unroll
            for (int c = 0; c < NH3; ++c) {
                wv[c] = wul[t][c];
                yv[c] = yrow[c];
            }
            // factorized logsumexp over cartesian one-hot cases:
            // groups [0,2) [2,6) [6,10) [10,18)
            float m = fmaxf(wv[0], wv[1]);
            ld += m + __logf(__expf(wv[0] - m) + __expf(wv[1] - m));
            m = fmaxf(fmaxf(wv[2], wv[3]), fmaxf(wv[4], wv[5]));
            ld += m + __logf(__expf(wv[2] - m) + __expf(wv[3] - m) +
                             __expf(wv[4] - m) + __expf(wv[5] - m));
            m = fmaxf(fmaxf(wv[6], wv[7]), fmaxf(wv[8], wv[9]));
            ld += m + __logf(__expf(wv[6] - m) + __expf(wv[7] - m) +
                             __expf(wv[8] - m) + __expf(wv[9] - m));
            m = wv[10];
#pragma unroll
            for (int i = 11; i < NH3; ++i) m = fmaxf(m, wv[i]);
            float s = 0.0f;
#pragma unroll
            for (int i = 10; i < NH3; ++i) s += __expf(wv[i] - m);
            ld += m + __logf(s);
        } else {
#pragma unroll
            for (int c = 0; c < NH3; ++c) { wv[c] = 0.0f; yv[c] = 0.0f; }
        }

        // 16-lane DPP reductions; group 0 (lanes 0..15) holds block totals
        ld = sum16(ld);
#pragma unroll
        for (int c = 0; c < NH3; ++c) {
            wv[c] = sum16(wv[c]);
            yv[c] = sum16(yv[c]);
        }
        if (t == 0) {
            float* slot = ws + (size_t)blockIdx.x * WSS;
#pragma unroll
            for (int c = 0; c < NH3; ++c) {
                slot[c]       = yv[c];       // ysum partial
                slot[NH3 + c] = wv[c];       // colsum(W_user) partial
            }
            slot[36] = ld;                   // log_denom partial
        }
    }
}

__global__ __launch_bounds__(256) void finalize_loss(
    const float* __restrict__ ws, float* __restrict__ out)
{
    __shared__ double part[4][37];
    const int t = threadIdx.x;
    const int w = t >> 6, l = t & 63;
    if (l < 37) {
        double a = 0.0;
        for (int b = w * (NBLK / 4); b < (w + 1) * (NBLK / 4); ++b)
            a += (double)ws[(size_t)b * WSS + l];   // lanes 0..36 coalesced
        part[w][l] = a;
    }
    __syncthreads();
    if (t == 0) {
        double tot[37];
#pragma unroll
        for (int c = 0; c < 37; ++c)
            tot[c] = part[0][c] + part[1][c] + part[2][c] + part[3][c];
        double s = 0.0;
#pragma unroll
        for (int c = 0; c < NH3; ++c)
            s += tot[NH3 + c] * tot[c];             // colsum(W_user) . ysum == sum(S)
        out[(size_t)NB * NH3] = (float)(-(s - tot[36]));
    }
}

extern "C" void kernel_launch(void* const* d_in, const int* in_sizes, int n_in,
                              void* d_out, int out_size, void* d_ws, size_t ws_size,
                              hipStream_t stream) {
    const float* x  = (const float*)d_in[0];
    const float* y  = (const float*)d_in[1];
    const float* W1 = (const float*)d_in[2];
    const float* b1 = (const float*)d_in[3];
    const float* W2 = (const float*)d_in[4];
    const float* b2 = (const float*)d_in[5];
    const float* W3 = (const float*)d_in[6];
    const float* b3 = (const float*)d_in[7];
    // d_in[8] (cases) folded into the factorized logsumexp.
    float* out = (float*)d_out;
    float* ws  = (float*)d_ws;

    fused_main<<<dim3(NBLK), dim3(256), 0, stream>>>(x, y, W1, b1, W2, b2, W3, b3, out, ws);
    finalize_loss<<<dim3(1), dim3(256), 0, stream>>>(ws, out);
}